// Round 2
// baseline (116.174 us; speedup 1.0000x reference)
//
#include <hip/hip_runtime.h>

// ConvQuadInterp3d: 3x3x3 replicate-padded stencil, quadratic peak refinement.
// Input  x: FP32, (2,1,10,512,512)
// Output: FP32, coords_max (2,1,3,10,512,512) ++ y_max (2,1,10,512,512)
// Coords channel order: ch0=d+dx2, ch1=h+dx1, ch2=w+dx0.
//
// R17: OCCUPANCY over tile size. R16 post-mortem: dur_us identical to R15's
// to one clock tick -> the 4x VMEM-issue cut was exactly cancelled by the
// 4x2 tile's register cost (~160+ VGPR, ~3 waves/SIMD). Kernel runs ~2 TB/s
// vs 6.3 achievable => latency-bound, not issue- or BW-bound. R17 drops the
// h-pairing: 4(w)x1(h) tile, V[3][3][6]=54 floats, __launch_bounds__(256,4)
// pins VGPR<=128 => >=4 waves/SIMD, 27 loads issued up-front per thread
// (27-deep MLP). Keeps R16's float4 loads/stores (6.75 load-instr + 1
// store-instr per output).
//
// NaN discipline: fast-math-safe by construction -- keep = |num| <= 0.7*|det|
// evaluated WITHOUT dividing; 1/det only taken when keep (=> det != 0).

constexpr int Dd = 10, Hh = 512, Ww = 512;
constexpr int HW  = Hh * Ww;        // 262144
constexpr int DHW = Dd * HW;        // 2621440
constexpr float BONUS_F = 10.0f;

__global__ __launch_bounds__(256, 4) void quad_kernel(
        const float* __restrict__ x, float* __restrict__ out) {
    const int tx = threadIdx.x;                        // lane 0..63
    const int w0 = (blockIdx.x << 8) + (tx << 2);      // 0..508, step 4
    const int h  = (blockIdx.y << 2) + threadIdx.y;    // one row per thread
    const int bd = blockIdx.z;                         // 0..19: b*Dd + d
    const int d  = bd % Dd;
    const int b  = bd / Dd;

    // replicate-clamped indices
    const int wl = (w0 == 0) ? 0 : w0 - 1;
    const int wr = (w0 + 4 > Ww - 1) ? Ww - 1 : w0 + 4;
    const int zm = (d == 0) ? bd : bd - 1, zp = (d == Dd - 1) ? bd : bd + 1;
    const int hr[3] = { (h == 0) ? 0 : h - 1, h, (h == Hh - 1) ? h : h + 1 };
    const int zz[3] = { zm, bd, zp };

    // V[z][r][k]: value at (plane z, row hr[r], w0-1+k), k=0..5.
    // 9 segments x (1 dwordx4 + 2 dword) = 27 load instrs for 4 outputs,
    // all independent and issued before first use (max MLP).
    float V[3][3][6];
#pragma unroll
    for (int z = 0; z < 3; ++z) {
        const float* pl = x + (size_t)zz[z] * HW;
#pragma unroll
        for (int r = 0; r < 3; ++r) {
            const float* rp = pl + (size_t)hr[r] * Ww;
            const float4 v4 = *reinterpret_cast<const float4*>(rp + w0);
            V[z][r][0] = rp[wl];
            V[z][r][1] = v4.x;  V[z][r][2] = v4.y;
            V[z][r][3] = v4.z;  V[z][r][4] = v4.w;
            V[z][r][5] = rp[wr];
        }
    }

    // Separable neighbor-max, shared across the 4-wide tile.
    // zc[r][j] = max over z(0..2), cols(j..j+2) of row r (full 3x3 slab)
    // pm[j]    = row-1 slab EXCLUDING the (z=1, col=j+1) center.
    // fmaxf(fmaxf(a,b),c) fuses to v_max3_f32.
    float zc[3][4], pm[4];
#pragma unroll
    for (int r = 0; r < 3; ++r)
#pragma unroll
        for (int j = 0; j < 4; ++j) {
            const float c0 = fmaxf(fmaxf(V[0][r][j], V[0][r][j+1]), V[0][r][j+2]);
            const float c1 = fmaxf(fmaxf(V[1][r][j], V[1][r][j+1]), V[1][r][j+2]);
            const float c2 = fmaxf(fmaxf(V[2][r][j], V[2][r][j+1]), V[2][r][j+2]);
            zc[r][j] = fmaxf(fmaxf(c0, c1), c2);
            if (r == 1)
                pm[j] = fmaxf(fmaxf(c0, c2), fmaxf(V[1][1][j], V[1][1][j+2]));
        }

    float rd[4], rh[4], rw[4], ry[4];               // compile-time indexed only

#pragma unroll
    for (int j = 0; j < 4; ++j) {
        const float xc = V[1][1][j+1];

        // 26-neighbor max: full slabs of rows 0,2 + center-excluded slab of
        // row 1, then clamp at 0. Exact exclusion of ONLY the center.
        const float nm = fmaxf(fmaxf(fmaxf(zc[0][j], zc[2][j]), pm[j]), 0.0f);
        const bool m = xc > nm;

        const float gx  = 0.5f * (V[1][1][j+2] - V[1][1][j]);
        const float gy  = 0.5f * (V[1][2][j+1] - V[1][0][j+1]);
        const float gs  = 0.5f * (V[2][1][j+1] - V[0][1][j+1]);
        const float dxx = V[1][1][j]   + V[1][1][j+2] - 2.0f * xc;
        const float dyy = V[1][0][j+1] + V[1][2][j+1] - 2.0f * xc;
        const float dss = V[0][1][j+1] + V[2][1][j+1] - 2.0f * xc;
        const float dxy = 0.25f * (V[1][0][j]   + V[1][2][j+2]
                                 - V[1][2][j]   - V[1][0][j+2]);
        const float dys = 0.25f * (V[0][0][j+1] + V[2][2][j+1]
                                 - V[2][0][j+1] - V[0][2][j+1]);
        const float dxs = 0.25f * (V[0][1][j]   + V[2][1][j+2]
                                 - V[2][1][j]   - V[0][1][j+2]);

        // Cramer numerators of H*s = g. Rm eps (<=1e-7) dropped: near-
        // singular dets rejected by keep, like ref's far>0.7 clamp.
        const float c00 = dyy * dss - dys * dys;
        const float c01 = dxy * dss - dys * dxs;
        const float c02 = dxy * dys - dyy * dxs;
        const float det = dxx * c00 - dxy * c01 + dxs * c02;
        const float t1  = gy * dss - dys * gs;
        const float t2  = gy * dys - dyy * gs;
        const float t3  = dxy * gs - gy * dxs;
        const float nx  = gx * c00 - dxy * t1 + dxs * t2;    // sx * det
        const float ny  = dxx * t1 - gx * c01 + dxs * t3;    // sy * det
        const float ns  = dxx * (-t2) - dxy * t3 + gx * c02; // ss * det

        // keep <=> m && det!=0 && all |num/det| <= 0.7, WITHOUT dividing.
        const float lim = 0.7f * fabsf(det);
        const bool keep = m && (fabsf(det) > 0.0f) &&
                          (fabsf(nx) <= lim) && (fabsf(ny) <= lim) &&
                          (fabsf(ns) <= lim);
        const float rdet = keep ? (1.0f / det) : 0.0f;
        const float dx0 = -nx * rdet;                // keep ? -nx/det : 0
        const float dx1 = -ny * rdet;
        const float dx2 = -ns * rdet;

        const float dy_ = 0.5f * (gx * dx0 + gy * dx1 + gs * dx2);

        rd[j] = (float)d + dx2;
        rh[j] = (float)h + dx1;
        rw[j] = (float)(w0 + j) + dx0;
        ry[j] = xc + dy_ + (m ? BONUS_F : 0.0f);
    }

    // 4 float4 stores: wave spans 1024B contiguous per instr.
    const size_t idx = (size_t)d * HW + (size_t)h * Ww + w0;
    *reinterpret_cast<float4*>(out + ((size_t)(b * 3 + 0)) * DHW + idx) =
        make_float4(rd[0], rd[1], rd[2], rd[3]);
    *reinterpret_cast<float4*>(out + ((size_t)(b * 3 + 1)) * DHW + idx) =
        make_float4(rh[0], rh[1], rh[2], rh[3]);
    *reinterpret_cast<float4*>(out + ((size_t)(b * 3 + 2)) * DHW + idx) =
        make_float4(rw[0], rw[1], rw[2], rw[3]);
    *reinterpret_cast<float4*>(out + (size_t)6 * DHW + (size_t)b * DHW + idx) =
        make_float4(ry[0], ry[1], ry[2], ry[3]);
}

extern "C" void kernel_launch(void* const* d_in, const int* in_sizes, int n_in,
                              void* d_out, int out_size, void* d_ws, size_t ws_size,
                              hipStream_t stream) {
    (void)in_sizes; (void)n_in; (void)out_size; (void)d_ws; (void)ws_size;
    const float* x = (const float*)d_in[0];
    float* out = (float*)d_out;
    dim3 block(64, 4, 1);
    dim3 grid(Ww / 256, Hh / 4, 2 * Dd);   // (2, 128, 20) = 5120 blocks
    quad_kernel<<<grid, block, 0, stream>>>(x, out);
}